// Round 3
// baseline (559.882 us; speedup 1.0000x reference)
//
#include <hip/hip_runtime.h>
#include <hip/hip_bf16.h>
#include <cstddef>
#include <cstdint>

// Problem constants (B=1)
#define S      2048
#define DIM    1024
#define HEADS  16
#define KVH    2
#define GQ     8
#define DH     64
#define CBS    64
#define SBS    64
#define NUMSEL 8
#define WIN    512
#define NCB    (S / CBS)      // 32
#define CDIM   (CBS * DH)     // 4096
#define QKVC   (HEADS * DH + 2 * KVH * DH)   // 1280
#define KOFF   (HEADS * DH)                  // 1024 (k cols start)
#define VOFF   (HEADS * DH + KVH * DH)       // 1152 (v cols start)
#define SCALE  0.125f
#define RMS_EPS 1.1920928955078125e-07f

typedef __attribute__((ext_vector_type(8))) short bf16x8;   // 8 bf16 in 4 VGPRs
typedef __attribute__((ext_vector_type(4))) float f32x4;

__device__ inline short f2bs(float f) {
    __hip_bfloat16 b = __float2bfloat16(f);
    return *(short*)&b;
}

// ---------------- wave (64-lane) reductions ----------------
__device__ inline float wave_sum(float v) {
    for (int o = 32; o > 0; o >>= 1) v += __shfl_xor(v, o);
    return v;
}

// ---------------- RMSNorm (writes fp32 + bf16 copies) ----------------
__global__ __launch_bounds__(256) void rmsnorm_kernel(
        const float* __restrict__ x, const float* __restrict__ g,
        float* __restrict__ xn, __hip_bfloat16* __restrict__ xnb) {
    int s = blockIdx.x, tid = threadIdx.x;
    const float4* row = (const float4*)(x + (size_t)s * DIM);
    float4 v = row[tid];
    float ss = v.x * v.x + v.y * v.y + v.z * v.z + v.w * v.w;
    ss = wave_sum(ss);
    __shared__ float red[4];
    if ((tid & 63) == 0) red[tid >> 6] = ss;
    __syncthreads();
    float tot = red[0] + red[1] + red[2] + red[3];
    float sc = rsqrtf(tot / (float)DIM + RMS_EPS);
    float4 gg = ((const float4*)g)[tid];
    float4 o;
    o.x = v.x * sc * gg.x; o.y = v.y * sc * gg.y;
    o.z = v.z * sc * gg.z; o.w = v.w * sc * gg.w;
    ((float4*)(xn + (size_t)s * DIM))[tid] = o;
    size_t b = (size_t)s * DIM + tid * 4;
    xnb[b + 0] = __float2bfloat16(o.x);
    xnb[b + 1] = __float2bfloat16(o.y);
    xnb[b + 2] = __float2bfloat16(o.z);
    xnb[b + 3] = __float2bfloat16(o.w);
}

// ---------------- fp32 -> bf16 cast ----------------
__global__ __launch_bounds__(256) void cast_bf16_kernel(
        const float* __restrict__ in, __hip_bfloat16* __restrict__ out, int n4) {
    int e = blockIdx.x * 256 + threadIdx.x;
    if (e >= n4) return;
    float4 v = ((const float4*)in)[e];
    out[4 * e + 0] = __float2bfloat16(v.x);
    out[4 * e + 1] = __float2bfloat16(v.y);
    out[4 * e + 2] = __float2bfloat16(v.z);
    out[4 * e + 3] = __float2bfloat16(v.w);
}

// ---------------- W (K,N) fp32 -> Wt (N,K) bf16, LDS-tiled transpose ----------------
__global__ __launch_bounds__(256) void transpose_cast_kernel(
        const float* __restrict__ W, short* __restrict__ Wt, int K, int N) {
    __shared__ float tile[64][65];
    int n0 = blockIdx.x * 64, k0 = blockIdx.y * 64;
    int tid = threadIdx.x;
    #pragma unroll
    for (int e = 0; e < 16; e++) {
        int idx = tid + e * 256;
        int r = idx >> 6, c = idx & 63;
        float v = 0.f;
        if (n0 + c < N) v = W[(size_t)(k0 + r) * N + n0 + c];
        tile[r][c] = v;
    }
    __syncthreads();
    #pragma unroll
    for (int e = 0; e < 16; e++) {
        int idx = tid + e * 256;
        int r = idx >> 6, c = idx & 63;      // r = n-in-tile, c = k-in-tile
        if (n0 + r < N)
            Wt[(size_t)(n0 + r) * K + k0 + c] = f2bs(tile[c][r]);
    }
}

// ---------------- extract V columns of qkv -> vb (S, KVH, DH) bf16 ----------------
__global__ __launch_bounds__(256) void cast_v_kernel(
        const float* __restrict__ qkv, short* __restrict__ vb) {
    int e = blockIdx.x * 256 + threadIdx.x;    // e4 over S*KVH*DH/4
    if (e >= S * KVH * DH / 4) return;
    int idx = e * 4;
    int tok = idx / (KVH * DH), rem = idx % (KVH * DH);
    float4 v = *(const float4*)(qkv + (size_t)tok * QKVC + VOFF + rem);
    vb[idx + 0] = f2bs(v.x);
    vb[idx + 1] = f2bs(v.y);
    vb[idx + 2] = f2bs(v.z);
    vb[idx + 3] = f2bs(v.w);
}

// ---------------- bf16 B^T MFMA GEMM: C = act(A(bf16,MxK) @ Bt^T(N,K bf16) + bias) ---
template <int BM, int BN, int WM, int WN, int ACT>
__global__ __launch_bounds__(256) void gemm_bt_kernel(
        const __hip_bfloat16* __restrict__ A, const short* __restrict__ Bt,
        const float* __restrict__ bias, float* __restrict__ C,
        int M, int N, int K) {
    constexpr int BK = 32;
    constexpr int TM = BM / (WM * 16);
    constexpr int TN = BN / (WN * 16);
    constexpr int LDK = BK + 8;
    __shared__ short As[BM][LDK];
    __shared__ short Bs[BN][LDK];
    int tid = threadIdx.x;
    int wave = tid >> 6, lane = tid & 63;
    int wm = wave % WM, wn = wave / WM;
    int m0 = wm * TM * 16, n0 = wn * TN * 16;
    int bm = blockIdx.y * BM, bn = blockIdx.x * BN;
    int lm = lane & 15, quad = lane >> 4;
    const short* Ash = (const short*)A;
    f32x4 acc[TM][TN] = {};
    for (int k0 = 0; k0 < K; k0 += BK) {
        #pragma unroll
        for (int e = 0; e < BM * BK / (256 * 8); e++) {
            int idx = (tid + e * 256) * 8;
            int r = idx >> 5, kk = idx & 31;
            *(bf16x8*)(&As[r][kk]) =
                *(const bf16x8*)(Ash + (size_t)(bm + r) * K + k0 + kk);
        }
        #pragma unroll
        for (int e = 0; e < BN * BK / (256 * 8); e++) {
            int idx = (tid + e * 256) * 8;
            int r = idx >> 5, kk = idx & 31;
            bf16x8 v = {};
            if (bn + r < N)
                v = *(const bf16x8*)(Bt + (size_t)(bn + r) * K + k0 + kk);
            *(bf16x8*)(&Bs[r][kk]) = v;
        }
        __syncthreads();
        bf16x8 af[TM], bf_[TN];
        #pragma unroll
        for (int i = 0; i < TM; i++)
            af[i] = *(const bf16x8*)(&As[m0 + i * 16 + lm][quad * 8]);
        #pragma unroll
        for (int j = 0; j < TN; j++)
            bf_[j] = *(const bf16x8*)(&Bs[n0 + j * 16 + lm][quad * 8]);
        #pragma unroll
        for (int i = 0; i < TM; i++)
            #pragma unroll
            for (int j = 0; j < TN; j++)
                acc[i][j] = __builtin_amdgcn_mfma_f32_16x16x32_bf16(
                    af[i], bf_[j], acc[i][j], 0, 0, 0);
        __syncthreads();
    }
    #pragma unroll
    for (int i = 0; i < TM; i++) {
        #pragma unroll
        for (int j = 0; j < TN; j++) {
            int gn = bn + n0 + j * 16 + lm;
            if (gn >= N) continue;
            #pragma unroll
            for (int r = 0; r < 4; r++) {
                int gm = bm + m0 + i * 16 + quad * 4 + r;
                float v = acc[i][j][r];
                if (bias) v += bias[gn];
                if (ACT == 2) v = 1.f / (1.f + expf(-v));
                C[(size_t)gm * N + gn] = v;
            }
        }
    }
}

// ---------------- bf16 MFMA GEMM, fp32 B (two-phase staging), split-K ---------------
template <int BM, int BN, int WM, int WN>
__global__ __launch_bounds__(256) void gemm_mfma_kernel(
        const __hip_bfloat16* __restrict__ A, const float* __restrict__ B,
        float* __restrict__ C, int M, int N, int K, int kslice) {
    constexpr int BK = 32;
    constexpr int TM = BM / (WM * 16);
    constexpr int TN = BN / (WN * 16);
    constexpr int LDK = BK + 8;
    constexpr int NB = BN * BK / 256;
    __shared__ __hip_bfloat16 As[BM][LDK];
    __shared__ __hip_bfloat16 Bs[BN][LDK];
    int tid = threadIdx.x;
    int wave = tid >> 6, lane = tid & 63;
    int wm = wave % WM, wn = wave / WM;
    int m0 = wm * TM * 16, n0 = wn * TN * 16;
    int bm = blockIdx.y * BM, bn = blockIdx.x * BN;
    int kbeg = blockIdx.z * kslice, kend = kbeg + kslice;
    int lm = lane & 15, quad = lane >> 4;
    f32x4 acc[TM][TN] = {};
    for (int k0 = kbeg; k0 < kend; k0 += BK) {
        #pragma unroll
        for (int e = 0; e < BM * BK / (256 * 8); e++) {
            int idx = (tid + e * 256) * 8;
            int r = idx >> 5, kk = idx & 31;
            *(bf16x8*)(&As[r][kk]) =
                *(const bf16x8*)(A + (size_t)(bm + r) * K + k0 + kk);
        }
        float tmpB[NB];
        #pragma unroll
        for (int e = 0; e < NB; e++) {
            int idx = tid + e * 256;
            int kk = idx / BN, n = idx % BN;
            tmpB[e] = B[(size_t)(k0 + kk) * N + bn + n];
        }
        #pragma unroll
        for (int e = 0; e < NB; e++) {
            int idx = tid + e * 256;
            int kk = idx / BN, n = idx % BN;
            Bs[n][kk] = __float2bfloat16(tmpB[e]);
        }
        __syncthreads();
        bf16x8 af[TM], bf_[TN];
        #pragma unroll
        for (int i = 0; i < TM; i++)
            af[i] = *(const bf16x8*)(&As[m0 + i * 16 + lm][quad * 8]);
        #pragma unroll
        for (int j = 0; j < TN; j++)
            bf_[j] = *(const bf16x8*)(&Bs[n0 + j * 16 + lm][quad * 8]);
        #pragma unroll
        for (int i = 0; i < TM; i++)
            #pragma unroll
            for (int j = 0; j < TN; j++)
                acc[i][j] = __builtin_amdgcn_mfma_f32_16x16x32_bf16(
                    af[i], bf_[j], acc[i][j], 0, 0, 0);
        __syncthreads();
    }
    size_t cbase = (size_t)blockIdx.z * M * N;
    #pragma unroll
    for (int i = 0; i < TM; i++) {
        #pragma unroll
        for (int j = 0; j < TN; j++) {
            int gn = bn + n0 + j * 16 + lm;
            #pragma unroll
            for (int r = 0; r < 4; r++) {
                int gm = bm + m0 + i * 16 + quad * 4 + r;
                C[cbase + (size_t)gm * N + gn] = acc[i][j][r];
            }
        }
    }
}

// ---------------- split-K fp32 GEMM (partials) — for the tiny W2 matmuls ----------------
__global__ __launch_bounds__(256) void gemm_splitk_kernel(
        const float* __restrict__ A, const float* __restrict__ B,
        float* __restrict__ P, int M, int N, int K, int kslice) {
    const int BM = 64, BN = 64, BK = 16;
    __shared__ float As[BK][BM + 4];
    __shared__ float Bs[BK][BN];
    int bm = blockIdx.y * BM, bn = blockIdx.x * BN;
    int z = blockIdx.z;
    int kbeg = z * kslice, kend = kbeg + kslice;
    int tid = threadIdx.x;
    int tx = tid & 15, ty = tid >> 4;
    float acc[4][4] = {{0.f}};
    for (int k0 = kbeg; k0 < kend; k0 += BK) {
        #pragma unroll
        for (int e = 0; e < 4; e++) {
            int idx = tid + e * 256;
            int m = idx >> 4, kk = idx & 15;
            int gm = bm + m;
            As[kk][m] = (gm < M) ? A[(size_t)gm * K + k0 + kk] : 0.f;
        }
        #pragma unroll
        for (int e = 0; e < 4; e++) {
            int idx = tid + e * 256;
            int kk = idx >> 6, n = idx & 63;
            int gn = bn + n;
            Bs[kk][n] = (gn < N) ? B[(size_t)(k0 + kk) * N + gn] : 0.f;
        }
        __syncthreads();
        #pragma unroll
        for (int kk = 0; kk < BK; kk++) {
            float a[4], b[4];
            #pragma unroll
            for (int i = 0; i < 4; i++) a[i] = As[kk][ty * 4 + i];
            #pragma unroll
            for (int j = 0; j < 4; j++) b[j] = Bs[kk][tx * 4 + j];
            #pragma unroll
            for (int i = 0; i < 4; i++)
                #pragma unroll
                for (int j = 0; j < 4; j++) acc[i][j] += a[i] * b[j];
        }
        __syncthreads();
    }
    #pragma unroll
    for (int i = 0; i < 4; i++) {
        int gm = bm + ty * 4 + i;
        if (gm >= M) continue;
        #pragma unroll
        for (int j = 0; j < 4; j++) {
            int gn = bn + tx * 4 + j;
            if (gn >= N) continue;
            P[((size_t)z * M + gm) * N + gn] = acc[i][j];
        }
    }
}

template <int ACT>
__global__ __launch_bounds__(256) void reduce_splitk_kernel(
        const float* __restrict__ P, const float* __restrict__ bias,
        float* __restrict__ C, int MN, int N, int splits) {
    int e = blockIdx.x * 256 + threadIdx.x;
    if (e >= MN) return;
    float s = 0.f;
    for (int z = 0; z < splits; z++) s += P[(size_t)z * MN + e];
    s += bias[e % N];
    if (ACT == 1) s = fmaxf(s, 0.f);
    C[e] = s;
}

// ---------------- rotary embedding -> bf16 rqb (S,H,DH), rkb (S,KVH,DH) ----------------
__global__ __launch_bounds__(256) void rotary_kernel(
        const float* __restrict__ qkv, short* __restrict__ rqb, short* __restrict__ rkb) {
    int s = blockIdx.x, tid = threadIdx.x;
    for (int p = tid; p < (HEADS + KVH) * (DH / 2); p += 256) {
        int t; const float* src; short* dst;
        if (p < HEADS * (DH / 2)) {
            int h = p >> 5; t = p & 31;
            src = qkv + (size_t)s * QKVC + h * DH + 2 * t;
            dst = rqb + (size_t)s * (HEADS * DH) + h * DH + 2 * t;
        } else {
            int pp = p - HEADS * (DH / 2);
            int h = pp >> 5; t = pp & 31;
            src = qkv + (size_t)s * QKVC + KOFF + h * DH + 2 * t;
            dst = rkb + (size_t)s * (KVH * DH) + h * DH + 2 * t;
        }
        float u0 = src[0], u1 = src[1];
        float freq = powf(10000.f, -((float)(2 * t) / (float)DH));
        float ang = (float)s * freq;
        float sn, cs;
        sincosf(ang, &sn, &cs);
        dst[0] = f2bs(u0 * cs - u1 * sn);
        dst[1] = f2bs(u1 * cs + u0 * sn);
    }
}

// ---------------- build compress-MLP input matrices (bf16 output) ----------------
__global__ __launch_bounds__(256) void build_cmat_kernel(
        const float* __restrict__ qkv, const float* __restrict__ k_pos,
        const float* __restrict__ v_pos, __hip_bfloat16* __restrict__ kcm,
        __hip_bfloat16* __restrict__ vcm) {
    int r = blockIdx.x;          // r = h*32 + w
    int h = r >> 5, w = r & 31;
    for (int e = threadIdx.x; e < CDIM; e += 256) {
        int i = e >> 6, d = e & 63;
        size_t qb = (size_t)(w * CBS + i) * QKVC;
        kcm[(size_t)r * CDIM + e] =
            __float2bfloat16(qkv[qb + KOFF + h * DH + d] + k_pos[(h * CBS + i) * DH + d]);
        vcm[(size_t)r * CDIM + e] =
            __float2bfloat16(qkv[qb + VOFF + h * DH + d] + v_pos[(h * CBS + i) * DH + d]);
    }
}

// ---------------- assemble ck/cv (fp32 + bf16): prepend mem_kv -> (KVH, 33, DH) -------
__global__ __launch_bounds__(256) void assemble_kernel(
        const float* __restrict__ ckb, const float* __restrict__ cvb,
        const float* __restrict__ mem_kv, float* __restrict__ ck, float* __restrict__ cv,
        short* __restrict__ ck16, short* __restrict__ cv16) {
    int e = blockIdx.x * 256 + threadIdx.x;
    if (e >= KVH * (NCB + 1) * DH) return;
    int d = e & 63;
    int j = (e >> 6) % (NCB + 1);
    int h = e / ((NCB + 1) * DH);
    float kv, vv;
    if (j == 0) {
        kv = mem_kv[0 * KVH * DH + h * DH + d];
        vv = mem_kv[1 * KVH * DH + h * DH + d];
    } else {
        kv = ckb[((size_t)h * NCB + j - 1) * DH + d];
        vv = cvb[((size_t)h * NCB + j - 1) * DH + d];
    }
    ck[e] = kv; cv[e] = vv;
    ck16[e] = f2bs(kv); cv16[e] = f2bs(vv);
}

// ---------------- block importance: imp[kvh][s][w] ----------------
__global__ __launch_bounds__(64) void imp_kernel(
        const float* __restrict__ qkv, const float* __restrict__ ck,
        float* __restrict__ imp) {
    int kvh = blockIdx.x, s = blockIdx.y, t = threadIdx.x;
    __shared__ float qg[GQ * DH];
    __shared__ float ckl[NCB * 65];
    for (int e = t; e < GQ * DH; e += 64) {
        int g = e >> 6, d = e & 63;
        qg[e] = qkv[(size_t)s * QKVC + (kvh * GQ + g) * DH + d];
    }
    for (int e = t; e < NCB * DH; e += 64) {
        int w = e >> 6, d = e & 63;
        ckl[w * 65 + d] = ck[((size_t)kvh * (NCB + 1) + 1 + w) * DH + d];
    }
    __syncthreads();
    if (t < NCB) {
        int w = t;
        float val;
        if (w * CBS + CBS - 1 < s) {
            float acc = 0.f;
            #pragma unroll
            for (int g = 0; g < GQ; g++) {
                const float* qp = qg + g * DH;
                const float* cp = ckl + w * 65;
                #pragma unroll 16
                for (int d = 0; d < DH; d++) acc += qp[d] * cp[d];
            }
            val = acc * SCALE * (1.f / (float)GQ);
        } else {
            val = -INFINITY;
        }
        imp[((size_t)kvh * S + s) * NCB + w] = val;
    }
}

// ---------------- top-8 selection (replicates lax.top_k stable ties) ----------------
__global__ __launch_bounds__(256) void select_kernel(
        const float* __restrict__ imp, int* __restrict__ sel) {
    int idx = blockIdx.x * 256 + threadIdx.x;
    if (idx >= KVH * S) return;
    const float* row = imp + (size_t)idx * NCB;
    float p[NCB];
    float m = -1000.f;
    for (int w = 0; w < NCB; w++) { p[w] = row[w]; m = fmaxf(m, p[w]); }
    float z = expf(-1000.f - m);
    for (int w = 0; w < NCB; w++) { p[w] = expf(p[w] - m); z += p[w]; }
    float inv = 1.f / z;
    bool used[NCB];
    for (int w = 0; w < NCB; w++) used[w] = false;
    for (int i = 0; i < NUMSEL; i++) {
        int best = 0; float bv = -1.f;
        for (int w = 0; w < NCB; w++) {
            if (!used[w]) {
                float pw = p[w] * inv;
                if (pw > bv) { bv = pw; best = w; }
            }
        }
        used[best] = true;
        sel[(size_t)idx * NUMSEL + i] = (bv > 1e-10f) ? best : -1;
    }
}

// ---------------- compressed attention, MFMA: block=(head, 64-q tile) ----------------
// 4 waves x 16 queries; single 33-key tile (padded to 64). Visibility mask is
// block-uniform: jj==0 || jj <= min(32, qb).
__global__ __launch_bounds__(256) void cattn_kernel(
        const float* __restrict__ qkv, const short* __restrict__ ck16,
        const short* __restrict__ cv16, const float* __restrict__ gates,
        float* __restrict__ attn) {
    int h = blockIdx.x, qb = blockIdx.y;
    int kvh = h >> 3;
    int tid = threadIdx.x;
    int wv = tid >> 6, lane = tid & 63;
    int lm = lane & 15, quad = lane >> 4;
    __shared__ short Qb[64][72];   // [q][d]
    __shared__ short Ks[64][72];   // [key][d] (keys 33..63 zero)
    __shared__ short Vt[64][72];   // [d][key]
    __shared__ short Pb[64][72];   // [q][key] probs (unnormalized)
    // stage Q (fp32 -> bf16)
    for (int e = tid; e < 1024; e += 256) {
        int q = e >> 4, d4 = (e & 15) * 4;
        float4 v = *(const float4*)(qkv + (size_t)(qb * 64 + q) * QKVC + h * DH + d4);
        Qb[q][d4 + 0] = f2bs(v.x); Qb[q][d4 + 1] = f2bs(v.y);
        Qb[q][d4 + 2] = f2bs(v.z); Qb[q][d4 + 3] = f2bs(v.w);
    }
    // stage K rows + V^T
    for (int e = tid; e < 512; e += 256) {
        int c8 = e >> 6, j = e & 63;
        bf16x8 kv = {}, vv = {};
        if (j < NCB + 1) {
            kv = *(const bf16x8*)(ck16 + ((size_t)kvh * (NCB + 1) + j) * DH + c8 * 8);
            vv = *(const bf16x8*)(cv16 + ((size_t)kvh * (NCB + 1) + j) * DH + c8 * 8);
        }
        #pragma unroll
        for (int t = 0; t < 8; t++) {
            Ks[j][c8 * 8 + t] = kv[t];
            Vt[c8 * 8 + t][j] = vv[t];
        }
    }
    __syncthreads();
    bf16x8 aq0 = *(const bf16x8*)&Qb[wv * 16 + lm][quad * 8];
    bf16x8 aq1 = *(const bf16x8*)&Qb[wv * 16 + lm][32 + quad * 8];
    int vismax = (qb < NCB) ? qb : NCB;       // jj<=vismax (plus jj==0) visible
    f32x4 sc[4];
    #pragma unroll
    for (int t = 0; t < 4; t++) {
        bf16x8 bk0 = *(const bf16x8*)&Ks[t * 16 + lm][quad * 8];
        bf16x8 bk1 = *(const bf16x8*)&Ks[t * 16 + lm][32 + quad * 8];
        f32x4 s4 = {0.f, 0.f, 0.f, 0.f};
        s4 = __builtin_amdgcn_mfma_f32_16x16x32_bf16(aq0, bk0, s4, 0, 0, 0);
        s4 = __builtin_amdgcn_mfma_f32_16x16x32_bf16(aq1, bk1, s4, 0, 0, 0);
        sc[t] = s4;
    }
    // softmax per row (row = quad*4+r, cols t*16+lm; reduce over 16 lm lanes)
    float l[4];
    float pr[4][4];
    #pragma unroll
    for (int r = 0; r < 4; r++) {
        float mx = -INFINITY;
        #pragma unroll
        for (int t = 0; t < 4; t++) {
            int jj = t * 16 + lm;
            bool vis = (jj == 0) || (jj <= vismax);
            float v = vis ? sc[t][r] * SCALE : -INFINITY;
            sc[t][r] = v;
            mx = fmaxf(mx, v);
        }
        #pragma unroll
        for (int o = 1; o < 16; o <<= 1) mx = fmaxf(mx, __shfl_xor(mx, o));
        float sum = 0.f;
        #pragma unroll
        for (int t = 0; t < 4; t++) {
            float p = __expf(sc[t][r] - mx);    // mx finite (jj==0 always visible)
            pr[r][t] = p;
            sum += p;
        }
        #pragma unroll
        for (int o = 1; o < 16; o <<= 1) sum += __shfl_xor(sum, o);
        l[r] = sum;
    }
    #pragma unroll
    for (int r = 0; r < 4; r++)
        #pragma unroll
        for (int t = 0; t < 4; t++)
            Pb[wv * 16 + quad * 4 + r][t * 16 + lm] = f2bs(pr[r][t]);
    __syncthreads();
    bf16x8 ap0 = *(const bf16x8*)&Pb[wv * 16 + lm][quad * 8];
    bf16x8 ap1 = *(const bf16x8*)&Pb[wv * 16 + lm][32 + quad * 8];
    f32x4 oacc[4];
    #pragma unroll
    for (int t = 0; t < 4; t++) {
        bf16x8 bv0 = *(const bf16x8*)&Vt[t * 16 + lm][quad * 8];
        bf16x8 bv1 = *(const bf16x8*)&Vt[t * 16 + lm][32 + quad * 8];
        f32x4 a = {0.f, 0.f, 0.f, 0.f};
        a = __builtin_amdgcn_mfma_f32_16x16x32_bf16(ap0, bv0, a, 0, 0, 0);
        a = __builtin_amdgcn_mfma_f32_16x16x32_bf16(ap1, bv1, a, 0, 0, 0);
        oacc[t] = a;
    }
    #pragma unroll
    for (int r = 0; r < 4; r++) {
        int spos = qb * 64 + wv * 16 + quad * 4 + r;
        float g0 = gates[((size_t)spos * HEADS + h) * 3 + 0];
        float f = g0 / l[r];
        #pragma unroll
        for (int t = 0; t < 4; t++)
            attn[(size_t)spos * (HEADS * DH) + h * DH + t * 16 + lm] = oacc[t][r] * f;
    }
}

// ---------------- fine attention: wave-private MFMA flash, K+V double-prefetch ------
// One 64-lane wave per (kvh, s). The 9-block loop is fully unrolled; K and V for
// block i+1 are loaded into registers while block i computes, so each chunk's
// critical path is compute-only (gather latency hidden). Invalid sel entries are
// clamped to block 0 for the (discarded) prefetch so the pipeline never bubbles.
// No barriers: Vt/Pb wave-private; per-wave in-order DS + lgkmcnt(0) drain.
__global__ __launch_bounds__(64, 2) void fattn_kernel(
        const short* __restrict__ rqb, const short* __restrict__ rkb,
        const short* __restrict__ vb, const int* __restrict__ sel,
        const float* __restrict__ gates, float* __restrict__ attn) {
    int kvh = blockIdx.x, s = blockIdx.y;
    int lane = threadIdx.x;
    int lm = lane & 15, quad = lane >> 4;
    __shared__ short Vt[64][68];               // [d][key] bf16 (V^T)
    __shared__ short Pb[16][68];               // [head][key] bf16 probs (rows 8-15 dup)
    const short* qp = rqb + (size_t)s * (HEADS * DH) + (size_t)(kvh * 8 + (lm & 7)) * DH;
    bf16x8 aq0 = *(const bf16x8*)(qp + quad * 8);
    bf16x8 aq1 = *(const bf16x8*)(qp + 32 + quad * 8);
    int bl[9];
    {
        const int4* sp = (const int4*)(sel + ((size_t)kvh * S + s) * NUMSEL);
        int4 s0 = sp[0], s1 = sp[1];
        bl[0] = s0.x; bl[1] = s0.y; bl[2] = s0.z; bl[3] = s0.w;
        bl[4] = s1.x; bl[5] = s1.y; bl[6] = s1.z; bl[7] = s1.w;
        bl[8] = s >> 6;
    }
    float m[4], l[4];
    f32x4 oacc[4];
    #pragma unroll
    for (int r = 0; r < 4; r++) {
        m[r] = -INFINITY; l[r] = 0.f;
        oacc[r] = (f32x4){0.f, 0.f, 0.f, 0.f};
    }
    bf16x8 kpre[2][4][2];                      // [parity][tile][frag]
    bf16x8 vpre[2][8];                         // [parity][row-chunk]
    {
        int w0 = bl[0] < 0 ? 0 : bl[0];
        #pragma unroll
        for (int t = 0; t < 4; t++) {
            const short* kp = rkb + ((size_t)(w0 * SBS + t * 16 + lm) * KVH + kvh) * DH;
            kpre[0][t][0] = *(const bf16x8*)(kp + quad * 8);
            kpre[0][t][1] = *(const bf16x8*)(kp + 32 + quad * 8);
        }
        const short* vp = vb + ((size_t)(w0 * SBS + lane) * KVH + kvh) * DH;
        #pragma unroll
        for (int r = 0; r < 8; r++) vpre[0][r] = *(const bf16x8*)(vp + r * 8);
    }
    #pragma unroll
    for (int i = 0; i < 9; i++) {
        const int p = i & 1;
        const int pn = p ^ 1;
        // prefetch K+V for block i+1 (clamped; issued before any compute of block i)
        if (i < 8) {
            int wn = bl[i + 1] < 0 ? 0 : bl[i + 1];
            #pragma unroll
            for (int t = 0; t < 4; t++) {
                const short* kp = rkb + ((size_t)(wn * SBS + t * 16 + lm) * KVH + kvh) * DH;
                kpre[pn][t][0] = *(const bf16x8*)(kp + quad * 8);
                kpre[pn][t][1] = *(const bf16x8*)(kp + 32 + quad * 8);
            }
            const short* vp = vb + ((size_t)(wn * SBS + lane) * KVH + kvh) * DH;
            #pragma unroll
            for (int r = 0; r < 8; r++) vpre[pn][r] = *(const bf16x8*)(vp + r * 8);
        }
        if (i < 8 && bl[i] < 0) continue;      // uniform across wave
        // stage V^T from resident vpre[p] (prev PV reads ordered by in-order DS)
        #pragma unroll
        for (int r = 0; r < 8; r++)
            #pragma unroll
            for (int t = 0; t < 8; t++) Vt[r * 8 + t][lane] = vpre[p][r][t];
        // QK from resident kpre[p]
        f32x4 sc[4];
        #pragma unroll
        for (int t = 0; t < 4; t++) {
            f32x4 s4 = {0.f, 0.f, 0.f, 0.f};
            s4 = __builtin_amdgcn_mfma_f32_16x16x32_bf16(aq0, kpre[p][t][0], s4, 0, 0, 0);
            s4 = __builtin_amdgcn_mfma_f32_16x16x32_bf16(aq1, kpre[p][t][1], s4, 0, 0, 0);
            sc[t] = s4;
        }
        // online softmax: row = head quad*4+r (quads 2/3 duplicate), cols = t*16+lm
        bool diag = (i == 8);
        #pragma unroll
        for (int r = 0; r < 4; r++) {
            float mx = -INFINITY;
            #pragma unroll
            for (int t = 0; t < 4; t++) {
                int jj = t * 16 + lm;
                bool vis = !diag || (jj <= (s & 63));
                float v = vis ? sc[t][r] * SCALE : -INFINITY;
                sc[t][r] = v;
                mx = fmaxf(mx, v);
            }
            #pragma unroll
            for (int o = 1; o < 16; o <<= 1) mx = fmaxf(mx, __shfl_xor(mx, o));
            float mn = fmaxf(m[r], mx);        // finite: >=1 visible key
            float al = __expf(m[r] - mn);
            float sum = 0.f;
            #pragma unroll
            for (int t = 0; t < 4; t++) {
                float pv_ = __expf(sc[t][r] - mn);
                sc[t][r] = pv_;                // reuse sc as P
                sum += pv_;
            }
            #pragma unroll
            for (int o = 1; o < 16; o <<= 1) sum += __shfl_xor(sum, o);
            l[r] = l[r] * al + sum;
            m[r] = mn;
            #pragma unroll
            for (int t = 0; t < 4; t++) oacc[t][r] *= al;
        }
        // write P (all quads; rows 8-15 duplicates feeding discarded C rows)
        #pragma unroll
        for (int r = 0; r < 4; r++)
            #pragma unroll
            for (int t = 0; t < 4; t++)
                Pb[quad * 4 + r][t * 16 + lm] = f2bs(sc[t][r]);
        asm volatile("s_waitcnt lgkmcnt(0)" ::: "memory");
        // PV
        bf16x8 ap0 = *(const bf16x8*)&Pb[lm][quad * 8];
        bf16x8 ap1 = *(const bf16x8*)&Pb[lm][32 + quad * 8];
        #pragma unroll
        for (int t = 0; t < 4; t++) {
            bf16x8 bv0 = *(const bf16x8*)&Vt[t * 16 + lm][quad * 8];
            bf16x8 bv1 = *(const bf16x8*)&Vt[t * 16 + lm][32 + quad * 8];
            oacc[t] = __builtin_amdgcn_mfma_f32_16x16x32_bf16(ap0, bv0, oacc[t], 0, 0, 0);
            oacc[t] = __builtin_amdgcn_mfma_f32_16x16x32_bf16(ap1, bv1, oacc[t], 0, 0, 0);
        }
    }
    if (quad < 2) {
        #pragma unroll
        for (int r = 0; r < 4; r++) {
            int head = kvh * 8 + quad * 4 + r;
            float fac = gates[((size_t)s * HEADS + head) * 3 + 1] / l[r];
            #pragma unroll
            for (int t = 0; t < 4; t++)
                attn[(size_t)s * (HEADS * DH) + head * DH + t * 16 + lm]
                    += oacc[t][r] * fac;
        }
    }
}

// ---------------- sliding window: MFMA flash, block=(head, 64-q tile) ----------------
// 4 waves x 16 queries; 9 key chunks of 64. ONE barrier per chunk: Vt is
// double-buffered (barrier k+1 proves all waves finished compute k before any
// wave overwrites buffer k); Pb is wave-private (wave wv only touches rows
// wv*16..wv*16+15) so its write->read needs only in-order DS + lgkmcnt(0).
// V loads issued at chunk top so they complete under the K-gather + QK MFMAs.
__global__ __launch_bounds__(256) void sattn_kernel(
        const short* __restrict__ rqb, const short* __restrict__ rkb,
        const short* __restrict__ vb, const float* __restrict__ gates,
        float* __restrict__ attn) {
    int h = blockIdx.x, qb = blockIdx.y;
    int kvh = h >> 3;
    int tid = threadIdx.x;
    int wv = tid >> 6, lane = tid & 63;
    int lm = lane & 15, quad = lane >> 4;
    __shared__ short Vt[2][64][72];   // [buf][d][key]
    __shared__ short Pb[64][72];      // [q][key] probs (wave-private rows)
    const short* qp = rqb + (size_t)(qb * 64 + wv * 16 + lm) * (HEADS * DH) + h * DH;
    bf16x8 aq0 = *(const bf16x8*)(qp + quad * 8);
    bf16x8 aq1 = *(const bf16x8*)(qp + 32 + quad * 8);
    int myrow = wv * 16 + quad * 4;            // + r
    int j0 = tid & 63, c80 = tid >> 6;         // V staging coords (row j0, chunks c80, c80+4)
    float m[4], l[4];
    f32x4 oacc[4];
    #pragma unroll
    for (int r = 0; r < 4; r++) { m[r] = -INFINITY; l[r] = 0.f; }
    #pragma unroll
    for (int t = 0; t < 4; t++) oacc[t] = (f32x4){0.f, 0.f, 0.f, 0.f};
    int nc = 0;
    for (int c = 0; c < 9; c++) {
        int kb = qb * 64 - WIN + c * 64;
        if (kb < 0) continue;                  // kb multiple of 64: all-or-nothing
        // issue V loads first (complete under K-gather + QK below)
        const short* vp = vb + ((size_t)(kb + j0) * KVH + kvh) * DH;
        bf16x8 vv0 = *(const bf16x8*)(vp + c80 * 8);
        bf16x8 vv1 = *(const bf16x8*)(vp + (c80 + 4) * 8);
        // scores: 4 key tiles, K B-frags direct from global rkb
        f32x4 sc[4];
        #pragma unroll
        for (int t = 0; t < 4; t++) {
            const short* kp = rkb + ((size_t)(kb + t * 16 + lm) * KVH + kvh) * DH;
            bf16x8 bk0 = *(const bf16x8*)(kp + quad * 8);
            bf16x8 bk1 = *(const bf16x8*)(kp + 32 + quad * 8);
            f32x4 s4 = {0.f, 0.f, 0.f, 0.f};
            s4 = __builtin_amdgcn_mfma_f32_16x16x32_bf16(aq0, bk0, s4, 0, 0, 0);
            s4 = __builtin_amdgcn_mfma_f32_16x16x32_bf16(aq1, bk1, s4, 0, 0, 0);
            sc[t] = s4;
        }
        // stage V^T into buffer nc&1
        short* vtb = &Vt[nc & 1][0][0];
        #pragma unroll
        for (int t = 0; t < 8; t++) vtb[(size_t)(c80 * 8 + t) * 72 + j0] = vv0[t];
        #pragma unroll
        for (int t = 0; t < 8; t++) vtb[(size_t)((c80 + 4) * 8 + t) * 72 + j0] = vv1[t];
        __syncthreads();                       // Vt[nc&1] visible to all waves
        // online softmax per row
        #pragma unroll
        for (int r = 0; r < 4; r++) {
            int row = myrow + r;
            float mx = -INFINITY;
            #pragma unroll
            for (int t = 0; t < 4; t++) {
                int jj = t * 16 + lm;
                bool vis = true;
                if (c == 0) vis = (jj >= row);          // window lower bound
                if (c == 8) vis = (jj <= row);          // causal
                float v = vis ? sc[t][r] * SCALE : -INFINITY;
                sc[t][r] = v;
                mx = fmaxf(mx, v);
            }
            #pragma unroll
            for (int o = 1; o < 16; o <<= 1) mx = fmaxf(mx, __shfl_xor(mx, o));
            float mn = fmaxf(m[r], mx);                 // finite: >=1 visible key
            float al = __expf(m[r] - mn);
            float sum = 0.f;
            #pragma unroll
            for (int t = 0; t < 4; t++) {
                float pv_ = __expf(sc[t][r] - mn);
                sc[t][r] = pv_;                         // reuse sc as P
                sum += pv_;
            }
            #pragma unroll
            for (int o = 1; o < 16; o <<= 1) sum += __shfl_xor(sum, o);
            l[r] = l[r] * al + sum;
            m[r] = mn;
            #pragma unroll
            for (int t = 0; t < 4; t++) oacc[t][r] *= al;
        }
        // write wave-private P rows
        #pragma unroll
        for (int r = 0; r < 4; r++)
            #pragma unroll
            for (int t = 0; t < 4; t++)
                Pb[myrow + r][t * 16 + lm] = f2bs(sc[t][r]);
        asm volatile("s_waitcnt lgkmcnt(0)" ::: "memory");
        // PV
        bf16x8 ap0 = *(const bf16x8*)&Pb[wv * 16 + lm][quad * 8];
        bf16x8 ap1 = *(const bf16x8*)&Pb[wv * 16 + lm][32 + quad * 8];
        #pragma unroll
        for (int t = 0; t < 4; t++) {
            bf16x8 bv0 = *(const bf16x8*)(vtb + (size_t)(t * 16 + lm) * 72 + quad * 8);
            bf16x8 bv1 = *(const bf16x8*)(vtb + (size_t)(t * 16 + lm) * 72 + 32 + quad * 8);
            oacc[t] = __builtin_amdgcn_mfma_f32_16x16x32_bf16(ap0, bv0, oacc[t], 0, 0, 0);
            oacc[t] = __builtin_amdgcn_mfma_f32_16x16x32_bf16(ap1, bv1, oacc[t], 0, 0, 0);
        }
        nc++;
    }
    #pragma unroll
    for (int r = 0; r < 4; r++) {
        int spos = qb * 64 + myrow + r;
        float g2 = gates[((size_t)spos * HEADS + h) * 3 + 2];
        float f = g2 / l[r];
        #pragma unroll
        for (int t = 0; t < 4; t++)
            attn[(size_t)spos * (HEADS * DH) + h * DH + t * 16 + lm] += oacc[t][r] * f;
    }
}

// ---------------- launch ----------------
extern "C" void kernel_launch(void* const* d_in, const int* in_sizes, int n_in,
                              void* d_out, int out_size, void* d_ws, size_t ws_size,
                              hipStream_t stream) {
    const float* x      = (const float*)d_in[0];
    const float* rms_g  = (const float*)d_in[1];
    const float* W_qkv  = (const float*)d_in[2];
    const float* k_pos  = (const float*)d_in[3];
    const float* v_pos  = (const float*)d_in[4];
    const float* mem_kv = (const float*)d_in[5];
    const float* kW1    = (const float*)d_in[6];
    const float* kb1    = (const float*)d_in[7];
    const float* kW2    = (const float*)d_in[8];
    const float* kb2    = (const float*)d_in[9];
    const float* vW1    = (const float*)d_in[10];
    const float* vb1    = (const float*)d_in[11];
    const float* vW2    = (const float*)d_in[12];
    const float* vb2    = (const float*)d_in[13];
    const float* W_comb = (const float*)d_in[14];
    const float* b_comb = (const float*)d_in[15];
    const float* W_out  = (const float*)d_in[16];
    float* out = (float*)d_out;

    // workspace layout (floats) — R (1048576 fl) time-multiplexed:
    //   steps 1-2.5: xnb; steps 4-8: MLP scratch; steps 15-16: attnb.
    float* ws    = (float*)d_ws;
    float* xn    = ws;                                     // 2097152
    float* qkv   = xn    + (size_t)S * DIM;                // 2621440
    short* rqb   = (short*)(qkv + (size_t)S * QKVC);       // 2097152 sh = 1048576 fl
    short* rkb   = (short*)((float*)rqb + 1048576);        // 262144 sh = 131072 fl
    float* R     = (float*)rkb + 131072;                   // 1048576
    float* ck    = R     + 1048576;                        // 4224
    float* cv    = ck    + (size_t)KVH * (NCB + 1) * DH;   // 4224
    short* ck16  = (short*)(cv + (size_t)KVH * (NCB + 1) * DH);  // 4224 sh = 2112 fl
    short* cv16  = (short*)((float*)ck16 + 2112);          // 2112 fl
    float* imp   = (float*)cv16 + 2112;                    // 131072
    float* gates = imp   + (size_t)KVH * S * NCB;          // 98304
    float* attn  = gates + (size_t)S * HEADS * 3;          // 2097152
    int*   sel   = (int*)(attn + (size_t)S * HEADS * DH);  // 32768 ints = 8192 fl
    float* WT    = attn + (size_t)S * HEADS * DH + 8192;
    short* wqkvT = (short*)WT;                             // 1280*1024 bf16 = 655360 fl
    short* woutT = (short*)(WT + 655360);                  // 1024*1024 bf16 = 524288 fl
    short* wcombT= (short*)(WT + 655360 + 524288);         // 48*1024 bf16 = 24576 fl

    __hip_bfloat16* xnb   = (__hip_bfloat16*)R;            // dead after gates
    __hip_bfloat16* kcmb  = (__hip_bfloat16*)R;            // 131072 fl
    __hip_bfloat16* vcmb  = (__hip_bfloat16*)(R + 131072); // 131072 fl
    float* khid  = R + 262144;                             // 262144 fl
    float* vhid  = R + 524288;                             // 262144 fl
    float* ckb   = R + 786432;                             // 4096 fl
    float* cvb   = R + 790528;                             // 4096 fl (ends 794624)
    __hip_bfloat16* attnb = (__hip_bfloat16*)R;            // reused after fattn
    short* vbb   = (short*)imp;   // 262144 bf16 = 131072 fl (imp dead after select)
    float* partW1 = attn;   // 2097152 (attn live only from step 12)
    float* partW2 = imp;    // 131072  (imp live only steps 10-11)

    // 0. pre-transpose+cast weights to bf16 B^T
    transpose_cast_kernel<<<dim3(QKVC / 64, DIM / 64), 256, 0, stream>>>(W_qkv, wqkvT, DIM, QKVC);
    transpose_cast_kernel<<<dim3(DIM / 64, DIM / 64), 256, 0, stream>>>(W_out, woutT, DIM, DIM);
    transpose_cast_kernel<<<dim3(1, DIM / 64), 256, 0, stream>>>(W_comb, wcombT, DIM, HEADS * 3);
    // 1. RMSNorm (fp32 + bf16)
    rmsnorm_kernel<<<S, 256, 0, stream>>>(x, rms_g, xn, xnb);
    // 2. QKV projection (bf16 B^T MFMA)
    gemm_bt_kernel<64, 64, 2, 2, 0><<<dim3(QKVC / 64, S / 64), 256, 0, stream>>>(
        xnb, wqkvT, nullptr, qkv, S, QKVC, DIM);
    // 2.5 gates = sigmoid(xn @ W_comb + b_comb)
    gemm_bt_kernel<64, 64, 2, 2, 2><<<dim3(1, S / 64), 256, 0, stream>>>(
        xnb, wcombT, b_comb, gates, S, HEADS * 3, DIM);
    // 3. rotary -> bf16 rqb, rkb
    rotary_kernel<<<S, 256, 0, stream>>>(qkv, rqb, rkb);
    // 4. compress-MLP inputs (bf16)
    build_cmat_kernel<<<KVH * NCB, 256, 0, stream>>>(qkv, k_pos, v_pos, kcmb, vcmb);
    // 5. k-MLP W1 (bf16 MFMA, split-K 8)
    gemm_mfma_kernel<64, 128, 1, 4><<<dim3(CDIM / 128, 1, 8), 256, 0, stream>>>(
        kcmb, kW1, partW1, 64, CDIM, CDIM, CDIM / 8);
    reduce_splitk_kernel<1><<<(64 * CDIM + 255) / 256, 256, 0, stream>>>(
        partW1, kb1, khid, 64 * CDIM, CDIM, 8);
    // 6. k-MLP W2 (fp32 split-K 32)
    gemm_splitk_kernel<<<dim3(1, 1, 32), 256, 0, stream>>>(khid, kW2, partW2, 64, DH, CDIM, CDIM / 32);
    reduce_splitk_kernel<0><<<(64 * DH + 255) / 256, 256, 0, stream>>>(partW2, kb2, ckb, 64 * DH, DH, 32);
    // 7. v-MLP
    gemm_mfma_kernel<64, 128, 1, 4><<<dim3(CDIM / 128, 1, 8), 256, 0, stream>>>(
        vcmb, vW1, partW1, 64, CDIM, CDIM, CDIM / 8);
    reduce_splitk_kernel<1><<<(64 * CDIM + 255) / 256, 256, 0, stream>>>(
        partW1, vb1, vhid, 64 * CDIM, CDIM, 8);
    gemm_splitk_kernel<<<dim3(1, 1, 32), 256, 0, stream>>>(vhid, vW2, partW2, 64, DH, CDIM, CDIM / 32);
    reduce_splitk_kernel<0><<<(64 * DH + 255) / 256, 256, 0, stream>>>(partW2, vb2, cvb, 64 * DH, DH, 32);
    // 8. assemble ck/cv (fp32 + bf16) with mem tokens
    assemble_kernel<<<(KVH * (NCB + 1) * DH + 255) / 256, 256, 0, stream>>>(
        ckb, cvb, mem_kv, ck, cv, ck16, cv16);
    // 10. block importance
    imp_kernel<<<dim3(KVH, S), 64, 0, stream>>>(qkv, ck, imp);
    // 11. top-8 selection
    select_kernel<<<(KVH * S + 255) / 256, 256, 0, stream>>>(imp, sel);
    // 11.5 cast V cols -> bf16 vbb
    cast_v_kernel<<<(S * KVH * DH / 4 + 255) / 256, 256, 0, stream>>>(qkv, vbb);
    // 12. compressed attention, MFMA (writes attn = g0*c_out)
    cattn_kernel<<<dim3(HEADS, S / 64), 256, 0, stream>>>(qkv, ck16, cv16, gates, attn);
    // 13. fine attention, wave-private pipelined MFMA flash (attn += g1*f_out)
    fattn_kernel<<<dim3(KVH, S), 64, 0, stream>>>(rqb, rkb, vbb, sel, gates, attn);
    // 14. sliding window, MFMA, 1 barrier/chunk (attn += g2*s_out)
    sattn_kernel<<<dim3(HEADS, S / 64), 256, 0, stream>>>(rqb, rkb, vbb, gates, attn);
    // 15. cast attn -> bf16
    cast_bf16_kernel<<<(S * HEADS * DH / 4 + 255) / 256, 256, 0, stream>>>(
        attn, attnb, S * HEADS * DH / 4);
    // 16. output projection (bf16 B^T MFMA)
    gemm_bt_kernel<64, 64, 2, 2, 0><<<dim3(DIM / 64, S / 64), 256, 0, stream>>>(
        attnb, woutT, nullptr, out, S, DIM, DIM);
}

// Round 4
// 540.326 us; speedup vs baseline: 1.0362x; 1.0362x over previous
//
#include <hip/hip_runtime.h>
#include <hip/hip_bf16.h>
#include <cstddef>
#include <cstdint>

// Problem constants (B=1)
#define S      2048
#define DIM    1024
#define HEADS  16
#define KVH    2
#define GQ     8
#define DH     64
#define CBS    64
#define SBS    64
#define NUMSEL 8
#define WIN    512
#define NCB    (S / CBS)      // 32
#define CDIM   (CBS * DH)     // 4096
#define QKVC   (HEADS * DH + 2 * KVH * DH)   // 1280
#define KOFF   (HEADS * DH)                  // 1024 (k cols start)
#define VOFF   (HEADS * DH + KVH * DH)       // 1152 (v cols start)
#define SCALE  0.125f
#define RMS_EPS 1.1920928955078125e-07f

typedef __attribute__((ext_vector_type(8))) short bf16x8;   // 8 bf16 in 4 VGPRs
typedef __attribute__((ext_vector_type(4))) float f32x4;

__device__ inline short f2bs(float f) {
    __hip_bfloat16 b = __float2bfloat16(f);
    return *(short*)&b;
}

// ---------------- wave (64-lane) reductions ----------------
__device__ inline float wave_sum(float v) {
    for (int o = 32; o > 0; o >>= 1) v += __shfl_xor(v, o);
    return v;
}

// ---------------- RMSNorm (writes fp32 + bf16 copies) ----------------
__global__ __launch_bounds__(256) void rmsnorm_kernel(
        const float* __restrict__ x, const float* __restrict__ g,
        float* __restrict__ xn, __hip_bfloat16* __restrict__ xnb) {
    int s = blockIdx.x, tid = threadIdx.x;
    const float4* row = (const float4*)(x + (size_t)s * DIM);
    float4 v = row[tid];
    float ss = v.x * v.x + v.y * v.y + v.z * v.z + v.w * v.w;
    ss = wave_sum(ss);
    __shared__ float red[4];
    if ((tid & 63) == 0) red[tid >> 6] = ss;
    __syncthreads();
    float tot = red[0] + red[1] + red[2] + red[3];
    float sc = rsqrtf(tot / (float)DIM + RMS_EPS);
    float4 gg = ((const float4*)g)[tid];
    float4 o;
    o.x = v.x * sc * gg.x; o.y = v.y * sc * gg.y;
    o.z = v.z * sc * gg.z; o.w = v.w * sc * gg.w;
    ((float4*)(xn + (size_t)s * DIM))[tid] = o;
    size_t b = (size_t)s * DIM + tid * 4;
    xnb[b + 0] = __float2bfloat16(o.x);
    xnb[b + 1] = __float2bfloat16(o.y);
    xnb[b + 2] = __float2bfloat16(o.z);
    xnb[b + 3] = __float2bfloat16(o.w);
}

// ---------------- fp32 -> bf16 cast ----------------
__global__ __launch_bounds__(256) void cast_bf16_kernel(
        const float* __restrict__ in, __hip_bfloat16* __restrict__ out, int n4) {
    int e = blockIdx.x * 256 + threadIdx.x;
    if (e >= n4) return;
    float4 v = ((const float4*)in)[e];
    out[4 * e + 0] = __float2bfloat16(v.x);
    out[4 * e + 1] = __float2bfloat16(v.y);
    out[4 * e + 2] = __float2bfloat16(v.z);
    out[4 * e + 3] = __float2bfloat16(v.w);
}

// ---------------- W (K,N) fp32 -> Wt (N,K) bf16, LDS-tiled transpose ----------------
__global__ __launch_bounds__(256) void transpose_cast_kernel(
        const float* __restrict__ W, short* __restrict__ Wt, int K, int N) {
    __shared__ float tile[64][65];
    int n0 = blockIdx.x * 64, k0 = blockIdx.y * 64;
    int tid = threadIdx.x;
    #pragma unroll
    for (int e = 0; e < 16; e++) {
        int idx = tid + e * 256;
        int r = idx >> 6, c = idx & 63;
        float v = 0.f;
        if (n0 + c < N) v = W[(size_t)(k0 + r) * N + n0 + c];
        tile[r][c] = v;
    }
    __syncthreads();
    #pragma unroll
    for (int e = 0; e < 16; e++) {
        int idx = tid + e * 256;
        int r = idx >> 6, c = idx & 63;      // r = n-in-tile, c = k-in-tile
        if (n0 + r < N)
            Wt[(size_t)(n0 + r) * K + k0 + c] = f2bs(tile[c][r]);
    }
}

// ---------------- extract V columns of qkv -> vb (S, KVH, DH) bf16 ----------------
__global__ __launch_bounds__(256) void cast_v_kernel(
        const float* __restrict__ qkv, short* __restrict__ vb) {
    int e = blockIdx.x * 256 + threadIdx.x;    // e4 over S*KVH*DH/4
    if (e >= S * KVH * DH / 4) return;
    int idx = e * 4;
    int tok = idx / (KVH * DH), rem = idx % (KVH * DH);
    float4 v = *(const float4*)(qkv + (size_t)tok * QKVC + VOFF + rem);
    vb[idx + 0] = f2bs(v.x);
    vb[idx + 1] = f2bs(v.y);
    vb[idx + 2] = f2bs(v.z);
    vb[idx + 3] = f2bs(v.w);
}

// ---------------- bf16 B^T MFMA GEMM: C = act(A(bf16,MxK) @ Bt^T(N,K bf16) + bias) ---
template <int BM, int BN, int WM, int WN, int ACT>
__global__ __launch_bounds__(256) void gemm_bt_kernel(
        const __hip_bfloat16* __restrict__ A, const short* __restrict__ Bt,
        const float* __restrict__ bias, float* __restrict__ C,
        int M, int N, int K) {
    constexpr int BK = 32;
    constexpr int TM = BM / (WM * 16);
    constexpr int TN = BN / (WN * 16);
    constexpr int LDK = BK + 8;
    __shared__ short As[BM][LDK];
    __shared__ short Bs[BN][LDK];
    int tid = threadIdx.x;
    int wave = tid >> 6, lane = tid & 63;
    int wm = wave % WM, wn = wave / WM;
    int m0 = wm * TM * 16, n0 = wn * TN * 16;
    int bm = blockIdx.y * BM, bn = blockIdx.x * BN;
    int lm = lane & 15, quad = lane >> 4;
    const short* Ash = (const short*)A;
    f32x4 acc[TM][TN] = {};
    for (int k0 = 0; k0 < K; k0 += BK) {
        #pragma unroll
        for (int e = 0; e < BM * BK / (256 * 8); e++) {
            int idx = (tid + e * 256) * 8;
            int r = idx >> 5, kk = idx & 31;
            *(bf16x8*)(&As[r][kk]) =
                *(const bf16x8*)(Ash + (size_t)(bm + r) * K + k0 + kk);
        }
        #pragma unroll
        for (int e = 0; e < BN * BK / (256 * 8); e++) {
            int idx = (tid + e * 256) * 8;
            int r = idx >> 5, kk = idx & 31;
            bf16x8 v = {};
            if (bn + r < N)
                v = *(const bf16x8*)(Bt + (size_t)(bn + r) * K + k0 + kk);
            *(bf16x8*)(&Bs[r][kk]) = v;
        }
        __syncthreads();
        bf16x8 af[TM], bf_[TN];
        #pragma unroll
        for (int i = 0; i < TM; i++)
            af[i] = *(const bf16x8*)(&As[m0 + i * 16 + lm][quad * 8]);
        #pragma unroll
        for (int j = 0; j < TN; j++)
            bf_[j] = *(const bf16x8*)(&Bs[n0 + j * 16 + lm][quad * 8]);
        #pragma unroll
        for (int i = 0; i < TM; i++)
            #pragma unroll
            for (int j = 0; j < TN; j++)
                acc[i][j] = __builtin_amdgcn_mfma_f32_16x16x32_bf16(
                    af[i], bf_[j], acc[i][j], 0, 0, 0);
        __syncthreads();
    }
    #pragma unroll
    for (int i = 0; i < TM; i++) {
        #pragma unroll
        for (int j = 0; j < TN; j++) {
            int gn = bn + n0 + j * 16 + lm;
            if (gn >= N) continue;
            #pragma unroll
            for (int r = 0; r < 4; r++) {
                int gm = bm + m0 + i * 16 + quad * 4 + r;
                float v = acc[i][j][r];
                if (bias) v += bias[gn];
                if (ACT == 2) v = 1.f / (1.f + expf(-v));
                C[(size_t)gm * N + gn] = v;
            }
        }
    }
}

// ---------------- bf16 MFMA GEMM, fp32 B (two-phase staging), split-K ---------------
template <int BM, int BN, int WM, int WN>
__global__ __launch_bounds__(256) void gemm_mfma_kernel(
        const __hip_bfloat16* __restrict__ A, const float* __restrict__ B,
        float* __restrict__ C, int M, int N, int K, int kslice) {
    constexpr int BK = 32;
    constexpr int TM = BM / (WM * 16);
    constexpr int TN = BN / (WN * 16);
    constexpr int LDK = BK + 8;
    constexpr int NB = BN * BK / 256;
    __shared__ __hip_bfloat16 As[BM][LDK];
    __shared__ __hip_bfloat16 Bs[BN][LDK];
    int tid = threadIdx.x;
    int wave = tid >> 6, lane = tid & 63;
    int wm = wave % WM, wn = wave / WM;
    int m0 = wm * TM * 16, n0 = wn * TN * 16;
    int bm = blockIdx.y * BM, bn = blockIdx.x * BN;
    int kbeg = blockIdx.z * kslice, kend = kbeg + kslice;
    int lm = lane & 15, quad = lane >> 4;
    f32x4 acc[TM][TN] = {};
    for (int k0 = kbeg; k0 < kend; k0 += BK) {
        #pragma unroll
        for (int e = 0; e < BM * BK / (256 * 8); e++) {
            int idx = (tid + e * 256) * 8;
            int r = idx >> 5, kk = idx & 31;
            *(bf16x8*)(&As[r][kk]) =
                *(const bf16x8*)(A + (size_t)(bm + r) * K + k0 + kk);
        }
        float tmpB[NB];
        #pragma unroll
        for (int e = 0; e < NB; e++) {
            int idx = tid + e * 256;
            int kk = idx / BN, n = idx % BN;
            tmpB[e] = B[(size_t)(k0 + kk) * N + bn + n];
        }
        #pragma unroll
        for (int e = 0; e < NB; e++) {
            int idx = tid + e * 256;
            int kk = idx / BN, n = idx % BN;
            Bs[n][kk] = __float2bfloat16(tmpB[e]);
        }
        __syncthreads();
        bf16x8 af[TM], bf_[TN];
        #pragma unroll
        for (int i = 0; i < TM; i++)
            af[i] = *(const bf16x8*)(&As[m0 + i * 16 + lm][quad * 8]);
        #pragma unroll
        for (int j = 0; j < TN; j++)
            bf_[j] = *(const bf16x8*)(&Bs[n0 + j * 16 + lm][quad * 8]);
        #pragma unroll
        for (int i = 0; i < TM; i++)
            #pragma unroll
            for (int j = 0; j < TN; j++)
                acc[i][j] = __builtin_amdgcn_mfma_f32_16x16x32_bf16(
                    af[i], bf_[j], acc[i][j], 0, 0, 0);
        __syncthreads();
    }
    size_t cbase = (size_t)blockIdx.z * M * N;
    #pragma unroll
    for (int i = 0; i < TM; i++) {
        #pragma unroll
        for (int j = 0; j < TN; j++) {
            int gn = bn + n0 + j * 16 + lm;
            #pragma unroll
            for (int r = 0; r < 4; r++) {
                int gm = bm + m0 + i * 16 + quad * 4 + r;
                C[cbase + (size_t)gm * N + gn] = acc[i][j][r];
            }
        }
    }
}

// ---------------- split-K fp32 GEMM (partials) — for the tiny W2 matmuls ----------------
__global__ __launch_bounds__(256) void gemm_splitk_kernel(
        const float* __restrict__ A, const float* __restrict__ B,
        float* __restrict__ P, int M, int N, int K, int kslice) {
    const int BM = 64, BN = 64, BK = 16;
    __shared__ float As[BK][BM + 4];
    __shared__ float Bs[BK][BN];
    int bm = blockIdx.y * BM, bn = blockIdx.x * BN;
    int z = blockIdx.z;
    int kbeg = z * kslice, kend = kbeg + kslice;
    int tid = threadIdx.x;
    int tx = tid & 15, ty = tid >> 4;
    float acc[4][4] = {{0.f}};
    for (int k0 = kbeg; k0 < kend; k0 += BK) {
        #pragma unroll
        for (int e = 0; e < 4; e++) {
            int idx = tid + e * 256;
            int m = idx >> 4, kk = idx & 15;
            int gm = bm + m;
            As[kk][m] = (gm < M) ? A[(size_t)gm * K + k0 + kk] : 0.f;
        }
        #pragma unroll
        for (int e = 0; e < 4; e++) {
            int idx = tid + e * 256;
            int kk = idx >> 6, n = idx & 63;
            int gn = bn + n;
            Bs[kk][n] = (gn < N) ? B[(size_t)(k0 + kk) * N + gn] : 0.f;
        }
        __syncthreads();
        #pragma unroll
        for (int kk = 0; kk < BK; kk++) {
            float a[4], b[4];
            #pragma unroll
            for (int i = 0; i < 4; i++) a[i] = As[kk][ty * 4 + i];
            #pragma unroll
            for (int j = 0; j < 4; j++) b[j] = Bs[kk][tx * 4 + j];
            #pragma unroll
            for (int i = 0; i < 4; i++)
                #pragma unroll
                for (int j = 0; j < 4; j++) acc[i][j] += a[i] * b[j];
        }
        __syncthreads();
    }
    #pragma unroll
    for (int i = 0; i < 4; i++) {
        int gm = bm + ty * 4 + i;
        if (gm >= M) continue;
        #pragma unroll
        for (int j = 0; j < 4; j++) {
            int gn = bn + tx * 4 + j;
            if (gn >= N) continue;
            P[((size_t)z * M + gm) * N + gn] = acc[i][j];
        }
    }
}

template <int ACT>
__global__ __launch_bounds__(256) void reduce_splitk_kernel(
        const float* __restrict__ P, const float* __restrict__ bias,
        float* __restrict__ C, int MN, int N, int splits) {
    int e = blockIdx.x * 256 + threadIdx.x;
    if (e >= MN) return;
    float s = 0.f;
    for (int z = 0; z < splits; z++) s += P[(size_t)z * MN + e];
    s += bias[e % N];
    if (ACT == 1) s = fmaxf(s, 0.f);
    C[e] = s;
}

// ---------------- rotary embedding -> bf16 rqb (S,H,DH), rkb (S,KVH,DH) ----------------
__global__ __launch_bounds__(256) void rotary_kernel(
        const float* __restrict__ qkv, short* __restrict__ rqb, short* __restrict__ rkb) {
    int s = blockIdx.x, tid = threadIdx.x;
    for (int p = tid; p < (HEADS + KVH) * (DH / 2); p += 256) {
        int t; const float* src; short* dst;
        if (p < HEADS * (DH / 2)) {
            int h = p >> 5; t = p & 31;
            src = qkv + (size_t)s * QKVC + h * DH + 2 * t;
            dst = rqb + (size_t)s * (HEADS * DH) + h * DH + 2 * t;
        } else {
            int pp = p - HEADS * (DH / 2);
            int h = pp >> 5; t = pp & 31;
            src = qkv + (size_t)s * QKVC + KOFF + h * DH + 2 * t;
            dst = rkb + (size_t)s * (KVH * DH) + h * DH + 2 * t;
        }
        float u0 = src[0], u1 = src[1];
        float freq = powf(10000.f, -((float)(2 * t) / (float)DH));
        float ang = (float)s * freq;
        float sn, cs;
        sincosf(ang, &sn, &cs);
        dst[0] = f2bs(u0 * cs - u1 * sn);
        dst[1] = f2bs(u1 * cs + u0 * sn);
    }
}

// ---------------- build compress-MLP input matrices (bf16 output) ----------------
__global__ __launch_bounds__(256) void build_cmat_kernel(
        const float* __restrict__ qkv, const float* __restrict__ k_pos,
        const float* __restrict__ v_pos, __hip_bfloat16* __restrict__ kcm,
        __hip_bfloat16* __restrict__ vcm) {
    int r = blockIdx.x;          // r = h*32 + w
    int h = r >> 5, w = r & 31;
    for (int e = threadIdx.x; e < CDIM; e += 256) {
        int i = e >> 6, d = e & 63;
        size_t qb = (size_t)(w * CBS + i) * QKVC;
        kcm[(size_t)r * CDIM + e] =
            __float2bfloat16(qkv[qb + KOFF + h * DH + d] + k_pos[(h * CBS + i) * DH + d]);
        vcm[(size_t)r * CDIM + e] =
            __float2bfloat16(qkv[qb + VOFF + h * DH + d] + v_pos[(h * CBS + i) * DH + d]);
    }
}

// ---------------- assemble ck/cv (fp32 + bf16): prepend mem_kv -> (KVH, 33, DH) -------
__global__ __launch_bounds__(256) void assemble_kernel(
        const float* __restrict__ ckb, const float* __restrict__ cvb,
        const float* __restrict__ mem_kv, float* __restrict__ ck, float* __restrict__ cv,
        short* __restrict__ ck16, short* __restrict__ cv16) {
    int e = blockIdx.x * 256 + threadIdx.x;
    if (e >= KVH * (NCB + 1) * DH) return;
    int d = e & 63;
    int j = (e >> 6) % (NCB + 1);
    int h = e / ((NCB + 1) * DH);
    float kv, vv;
    if (j == 0) {
        kv = mem_kv[0 * KVH * DH + h * DH + d];
        vv = mem_kv[1 * KVH * DH + h * DH + d];
    } else {
        kv = ckb[((size_t)h * NCB + j - 1) * DH + d];
        vv = cvb[((size_t)h * NCB + j - 1) * DH + d];
    }
    ck[e] = kv; cv[e] = vv;
    ck16[e] = f2bs(kv); cv16[e] = f2bs(vv);
}

// ---------------- block importance: imp[kvh][s][w] ----------------
__global__ __launch_bounds__(64) void imp_kernel(
        const float* __restrict__ qkv, const float* __restrict__ ck,
        float* __restrict__ imp) {
    int kvh = blockIdx.x, s = blockIdx.y, t = threadIdx.x;
    __shared__ float qg[GQ * DH];
    __shared__ float ckl[NCB * 65];
    for (int e = t; e < GQ * DH; e += 64) {
        int g = e >> 6, d = e & 63;
        qg[e] = qkv[(size_t)s * QKVC + (kvh * GQ + g) * DH + d];
    }
    for (int e = t; e < NCB * DH; e += 64) {
        int w = e >> 6, d = e & 63;
        ckl[w * 65 + d] = ck[((size_t)kvh * (NCB + 1) + 1 + w) * DH + d];
    }
    __syncthreads();
    if (t < NCB) {
        int w = t;
        float val;
        if (w * CBS + CBS - 1 < s) {
            float acc = 0.f;
            #pragma unroll
            for (int g = 0; g < GQ; g++) {
                const float* qp = qg + g * DH;
                const float* cp = ckl + w * 65;
                #pragma unroll 16
                for (int d = 0; d < DH; d++) acc += qp[d] * cp[d];
            }
            val = acc * SCALE * (1.f / (float)GQ);
        } else {
            val = -INFINITY;
        }
        imp[((size_t)kvh * S + s) * NCB + w] = val;
    }
}

// ---------------- top-8 selection (replicates lax.top_k stable ties) ----------------
__global__ __launch_bounds__(256) void select_kernel(
        const float* __restrict__ imp, int* __restrict__ sel) {
    int idx = blockIdx.x * 256 + threadIdx.x;
    if (idx >= KVH * S) return;
    const float* row = imp + (size_t)idx * NCB;
    float p[NCB];
    float m = -1000.f;
    for (int w = 0; w < NCB; w++) { p[w] = row[w]; m = fmaxf(m, p[w]); }
    float z = expf(-1000.f - m);
    for (int w = 0; w < NCB; w++) { p[w] = expf(p[w] - m); z += p[w]; }
    float inv = 1.f / z;
    bool used[NCB];
    for (int w = 0; w < NCB; w++) used[w] = false;
    for (int i = 0; i < NUMSEL; i++) {
        int best = 0; float bv = -1.f;
        for (int w = 0; w < NCB; w++) {
            if (!used[w]) {
                float pw = p[w] * inv;
                if (pw > bv) { bv = pw; best = w; }
            }
        }
        used[best] = true;
        sel[(size_t)idx * NUMSEL + i] = (bv > 1e-10f) ? best : -1;
    }
}

// ---------------- compressed attention, MFMA: block=(head, 64-q tile) ----------------
// 4 waves x 16 queries; single 33-key tile (padded to 64). Visibility mask is
// block-uniform: jj==0 || jj <= min(32, qb).
__global__ __launch_bounds__(256) void cattn_kernel(
        const float* __restrict__ qkv, const short* __restrict__ ck16,
        const short* __restrict__ cv16, const float* __restrict__ gates,
        float* __restrict__ attn) {
    int h = blockIdx.x, qb = blockIdx.y;
    int kvh = h >> 3;
    int tid = threadIdx.x;
    int wv = tid >> 6, lane = tid & 63;
    int lm = lane & 15, quad = lane >> 4;
    __shared__ short Qb[64][72];   // [q][d]
    __shared__ short Ks[64][72];   // [key][d] (keys 33..63 zero)
    __shared__ short Vt[64][72];   // [d][key]
    __shared__ short Pb[64][72];   // [q][key] probs (unnormalized)
    // stage Q (fp32 -> bf16)
    for (int e = tid; e < 1024; e += 256) {
        int q = e >> 4, d4 = (e & 15) * 4;
        float4 v = *(const float4*)(qkv + (size_t)(qb * 64 + q) * QKVC + h * DH + d4);
        Qb[q][d4 + 0] = f2bs(v.x); Qb[q][d4 + 1] = f2bs(v.y);
        Qb[q][d4 + 2] = f2bs(v.z); Qb[q][d4 + 3] = f2bs(v.w);
    }
    // stage K rows + V^T
    for (int e = tid; e < 512; e += 256) {
        int c8 = e >> 6, j = e & 63;
        bf16x8 kv = {}, vv = {};
        if (j < NCB + 1) {
            kv = *(const bf16x8*)(ck16 + ((size_t)kvh * (NCB + 1) + j) * DH + c8 * 8);
            vv = *(const bf16x8*)(cv16 + ((size_t)kvh * (NCB + 1) + j) * DH + c8 * 8);
        }
        #pragma unroll
        for (int t = 0; t < 8; t++) {
            Ks[j][c8 * 8 + t] = kv[t];
            Vt[c8 * 8 + t][j] = vv[t];
        }
    }
    __syncthreads();
    bf16x8 aq0 = *(const bf16x8*)&Qb[wv * 16 + lm][quad * 8];
    bf16x8 aq1 = *(const bf16x8*)&Qb[wv * 16 + lm][32 + quad * 8];
    int vismax = (qb < NCB) ? qb : NCB;       // jj<=vismax (plus jj==0) visible
    f32x4 sc[4];
    #pragma unroll
    for (int t = 0; t < 4; t++) {
        bf16x8 bk0 = *(const bf16x8*)&Ks[t * 16 + lm][quad * 8];
        bf16x8 bk1 = *(const bf16x8*)&Ks[t * 16 + lm][32 + quad * 8];
        f32x4 s4 = {0.f, 0.f, 0.f, 0.f};
        s4 = __builtin_amdgcn_mfma_f32_16x16x32_bf16(aq0, bk0, s4, 0, 0, 0);
        s4 = __builtin_amdgcn_mfma_f32_16x16x32_bf16(aq1, bk1, s4, 0, 0, 0);
        sc[t] = s4;
    }
    // softmax per row (row = quad*4+r, cols t*16+lm; reduce over 16 lm lanes)
    float l[4];
    float pr[4][4];
    #pragma unroll
    for (int r = 0; r < 4; r++) {
        float mx = -INFINITY;
        #pragma unroll
        for (int t = 0; t < 4; t++) {
            int jj = t * 16 + lm;
            bool vis = (jj == 0) || (jj <= vismax);
            float v = vis ? sc[t][r] * SCALE : -INFINITY;
            sc[t][r] = v;
            mx = fmaxf(mx, v);
        }
        #pragma unroll
        for (int o = 1; o < 16; o <<= 1) mx = fmaxf(mx, __shfl_xor(mx, o));
        float sum = 0.f;
        #pragma unroll
        for (int t = 0; t < 4; t++) {
            float p = __expf(sc[t][r] - mx);    // mx finite (jj==0 always visible)
            pr[r][t] = p;
            sum += p;
        }
        #pragma unroll
        for (int o = 1; o < 16; o <<= 1) sum += __shfl_xor(sum, o);
        l[r] = sum;
    }
    #pragma unroll
    for (int r = 0; r < 4; r++)
        #pragma unroll
        for (int t = 0; t < 4; t++)
            Pb[wv * 16 + quad * 4 + r][t * 16 + lm] = f2bs(pr[r][t]);
    __syncthreads();
    bf16x8 ap0 = *(const bf16x8*)&Pb[wv * 16 + lm][quad * 8];
    bf16x8 ap1 = *(const bf16x8*)&Pb[wv * 16 + lm][32 + quad * 8];
    f32x4 oacc[4];
    #pragma unroll
    for (int t = 0; t < 4; t++) {
        bf16x8 bv0 = *(const bf16x8*)&Vt[t * 16 + lm][quad * 8];
        bf16x8 bv1 = *(const bf16x8*)&Vt[t * 16 + lm][32 + quad * 8];
        f32x4 a = {0.f, 0.f, 0.f, 0.f};
        a = __builtin_amdgcn_mfma_f32_16x16x32_bf16(ap0, bv0, a, 0, 0, 0);
        a = __builtin_amdgcn_mfma_f32_16x16x32_bf16(ap1, bv1, a, 0, 0, 0);
        oacc[t] = a;
    }
    #pragma unroll
    for (int r = 0; r < 4; r++) {
        int spos = qb * 64 + wv * 16 + quad * 4 + r;
        float g0 = gates[((size_t)spos * HEADS + h) * 3 + 0];
        float f = g0 / l[r];
        #pragma unroll
        for (int t = 0; t < 4; t++)
            attn[(size_t)spos * (HEADS * DH) + h * DH + t * 16 + lm] = oacc[t][r] * f;
    }
}

// ---------------- fine attention: 2 waves per (kvh, s), split key blocks ------------
// Wave 0 handles sel[0..3], wave 1 handles sel[4..7] + the diagonal block.
// Each wave runs a wave-private flash loop (R1 body: Vt/Pb private slices, no
// barriers inside; in-order DS + lgkmcnt(0) drain), then the two partial
// (m, l, O) states are merged through LDS (aliased onto wave 1's dead Vt/Pb).
// Wave 1 always has >=1 visible key (diagonal), so its m is finite; wave 0 may
// be empty (early tokens) and merges as exp(-inf)=0.
__global__ __launch_bounds__(128) void fattn_kernel(
        const short* __restrict__ rqb, const short* __restrict__ rkb,
        const short* __restrict__ vb, const int* __restrict__ sel,
        const float* __restrict__ gates, float* __restrict__ attn) {
    int kvh = blockIdx.x, s = blockIdx.y;
    int tid = threadIdx.x;
    int wv = tid >> 6, lane = tid & 63;
    int lm = lane & 15, quad = lane >> 4;
    __shared__ short Vt[2][64][68];            // per-wave [d][key] (V^T)
    __shared__ short Pb[2][16][68];            // per-wave [head][key] (rows 8-15 dup)
    const short* qp = rqb + (size_t)s * (HEADS * DH) + (size_t)(kvh * 8 + (lm & 7)) * DH;
    bf16x8 aq0 = *(const bf16x8*)(qp + quad * 8);
    bf16x8 aq1 = *(const bf16x8*)(qp + 32 + quad * 8);
    int bl[9];
    {
        const int4* sp = (const int4*)(sel + ((size_t)kvh * S + s) * NUMSEL);
        int4 s0 = sp[0], s1 = sp[1];
        bl[0] = s0.x; bl[1] = s0.y; bl[2] = s0.z; bl[3] = s0.w;
        bl[4] = s1.x; bl[5] = s1.y; bl[6] = s1.z; bl[7] = s1.w;
        bl[8] = s >> 6;
    }
    float m[4], l[4];
    f32x4 oacc[4];
    #pragma unroll
    for (int r = 0; r < 4; r++) {
        m[r] = -INFINITY; l[r] = 0.f;
        oacc[r] = (f32x4){0.f, 0.f, 0.f, 0.f};
    }
    int ibeg = wv ? 4 : 0;
    int iend = wv ? 9 : 4;
    for (int i = ibeg; i < iend; i++) {
        int w = bl[i];
        if (i < NUMSEL && w < 0) continue;     // uniform across wave
        // issue V loads (this lane's key row) — complete under QK below
        const short* vp = vb + ((size_t)(w * SBS + lane) * KVH + kvh) * DH;
        bf16x8 vv[8];
        #pragma unroll
        for (int r = 0; r < 8; r++) vv[r] = *(const bf16x8*)(vp + r * 8);
        // QK scores: 4 key tiles, K B-frags direct from global rkb
        f32x4 sc[4];
        #pragma unroll
        for (int t = 0; t < 4; t++) {
            const short* kp = rkb + ((size_t)(w * SBS + t * 16 + lm) * KVH + kvh) * DH;
            bf16x8 bk0 = *(const bf16x8*)(kp + quad * 8);
            bf16x8 bk1 = *(const bf16x8*)(kp + 32 + quad * 8);
            f32x4 s4 = {0.f, 0.f, 0.f, 0.f};
            s4 = __builtin_amdgcn_mfma_f32_16x16x32_bf16(aq0, bk0, s4, 0, 0, 0);
            s4 = __builtin_amdgcn_mfma_f32_16x16x32_bf16(aq1, bk1, s4, 0, 0, 0);
            sc[t] = s4;
        }
        // stage V^T (lane-consecutive columns: conflict-free)
        #pragma unroll
        for (int r = 0; r < 8; r++)
            #pragma unroll
            for (int t = 0; t < 8; t++) Vt[wv][r * 8 + t][lane] = vv[r][t];
        // online softmax: row = head quad*4+r (quads 2/3 duplicate), cols = t*16+lm
        bool diag = (i == 8);
        #pragma unroll
        for (int r = 0; r < 4; r++) {
            float mx = -INFINITY;
            #pragma unroll
            for (int t = 0; t < 4; t++) {
                int jj = t * 16 + lm;
                bool vis = !diag || (jj <= (s & 63));
                float v = vis ? sc[t][r] * SCALE : -INFINITY;
                sc[t][r] = v;
                mx = fmaxf(mx, v);
            }
            #pragma unroll
            for (int o = 1; o < 16; o <<= 1) mx = fmaxf(mx, __shfl_xor(mx, o));
            float mn = fmaxf(m[r], mx);        // finite: >=1 visible key this iter
            float al = __expf(m[r] - mn);
            float sum = 0.f;
            #pragma unroll
            for (int t = 0; t < 4; t++) {
                float pv_ = __expf(sc[t][r] - mn);
                sc[t][r] = pv_;                // reuse sc as P
                sum += pv_;
            }
            #pragma unroll
            for (int o = 1; o < 16; o <<= 1) sum += __shfl_xor(sum, o);
            l[r] = l[r] * al + sum;
            m[r] = mn;
            #pragma unroll
            for (int t = 0; t < 4; t++) oacc[t][r] *= al;
        }
        // write P (all quads; rows 8-15 duplicates feeding discarded C rows)
        #pragma unroll
        for (int r = 0; r < 4; r++)
            #pragma unroll
            for (int t = 0; t < 4; t++)
                Pb[wv][quad * 4 + r][t * 16 + lm] = f2bs(sc[t][r]);
        asm volatile("s_waitcnt lgkmcnt(0)" ::: "memory");
        // PV
        bf16x8 ap0 = *(const bf16x8*)&Pb[wv][lm][quad * 8];
        bf16x8 ap1 = *(const bf16x8*)&Pb[wv][lm][32 + quad * 8];
        #pragma unroll
        for (int t = 0; t < 4; t++) {
            bf16x8 bv0 = *(const bf16x8*)&Vt[wv][t * 16 + lm][quad * 8];
            bf16x8 bv1 = *(const bf16x8*)&Vt[wv][t * 16 + lm][32 + quad * 8];
            oacc[t] = __builtin_amdgcn_mfma_f32_16x16x32_bf16(ap0, bv0, oacc[t], 0, 0, 0);
            oacc[t] = __builtin_amdgcn_mfma_f32_16x16x32_bf16(ap1, bv1, oacc[t], 0, 0, 0);
        }
    }
    // -------- merge the two waves' partial flash states --------
    __syncthreads();                           // both waves done with Vt/Pb
    float* O1  = (float*)&Vt[1][0][0];         // 8 heads x 64 d  (8 KB <= 8704 B)
    float* ML1 = (float*)&Pb[1][0][0];         // 8 heads x {m,l}
    if (wv == 1 && quad < 2) {
        #pragma unroll
        for (int r = 0; r < 4; r++) {
            int head = quad * 4 + r;
            #pragma unroll
            for (int t = 0; t < 4; t++)
                O1[head * 64 + t * 16 + lm] = oacc[t][r];
            if (lm == 0) {
                ML1[head * 2 + 0] = m[r];
                ML1[head * 2 + 1] = l[r];
            }
        }
    }
    __syncthreads();
    if (wv == 0 && quad < 2) {
        #pragma unroll
        for (int r = 0; r < 4; r++) {
            int head = quad * 4 + r;
            float m1 = ML1[head * 2 + 0], l1 = ML1[head * 2 + 1];
            float ms = fmaxf(m[r], m1);        // finite (wave 1 has diagonal)
            float a0 = __expf(m[r] - ms), a1 = __expf(m1 - ms);
            float lt = l[r] * a0 + l1 * a1;
            float fac = gates[((size_t)s * HEADS + kvh * 8 + head) * 3 + 1] / lt;
            #pragma unroll
            for (int t = 0; t < 4; t++)
                attn[(size_t)s * (HEADS * DH) + (kvh * 8 + head) * DH + t * 16 + lm]
                    += (oacc[t][r] * a0 + O1[head * 64 + t * 16 + lm] * a1) * fac;
        }
    }
}

// ---------------- sliding window: MFMA flash, block=(head, 64-q tile) ----------------
// 4 waves x 16 queries; 9 key chunks of 64. ONE barrier per chunk: Vt is
// double-buffered (barrier k+1 proves all waves finished compute k before any
// wave overwrites buffer k); Pb is wave-private (wave wv only touches rows
// wv*16..wv*16+15) so its write->read needs only in-order DS + lgkmcnt(0).
// V loads issued at chunk top so they complete under the K-gather + QK MFMAs.
__global__ __launch_bounds__(256) void sattn_kernel(
        const short* __restrict__ rqb, const short* __restrict__ rkb,
        const short* __restrict__ vb, const float* __restrict__ gates,
        float* __restrict__ attn) {
    int h = blockIdx.x, qb = blockIdx.y;
    int kvh = h >> 3;
    int tid = threadIdx.x;
    int wv = tid >> 6, lane = tid & 63;
    int lm = lane & 15, quad = lane >> 4;
    __shared__ short Vt[2][64][72];   // [buf][d][key]
    __shared__ short Pb[64][72];      // [q][key] probs (wave-private rows)
    const short* qp = rqb + (size_t)(qb * 64 + wv * 16 + lm) * (HEADS * DH) + h * DH;
    bf16x8 aq0 = *(const bf16x8*)(qp + quad * 8);
    bf16x8 aq1 = *(const bf16x8*)(qp + 32 + quad * 8);
    int myrow = wv * 16 + quad * 4;            // + r
    int j0 = tid & 63, c80 = tid >> 6;         // V staging coords (row j0, chunks c80, c80+4)
    float m[4], l[4];
    f32x4 oacc[4];
    #pragma unroll
    for (int r = 0; r < 4; r++) { m[r] = -INFINITY; l[r] = 0.f; }
    #pragma unroll
    for (int t = 0; t < 4; t++) oacc[t] = (f32x4){0.f, 0.f, 0.f, 0.f};
    int nc = 0;
    for (int c = 0; c < 9; c++) {
        int kb = qb * 64 - WIN + c * 64;
        if (kb < 0) continue;                  // kb multiple of 64: all-or-nothing
        // issue V loads first (complete under K-gather + QK below)
        const short* vp = vb + ((size_t)(kb + j0) * KVH + kvh) * DH;
        bf16x8 vv0 = *(const bf16x8*)(vp + c80 * 8);
        bf16x8 vv1 = *(const bf16x8*)(vp + (c80 + 4) * 8);
        // scores: 4 key tiles, K B-frags direct from global rkb
        f32x4 sc[4];
        #pragma unroll
        for (int t = 0; t < 4; t++) {
            const short* kp = rkb + ((size_t)(kb + t * 16 + lm) * KVH + kvh) * DH;
            bf16x8 bk0 = *(const bf16x8*)(kp + quad * 8);
            bf16x8 bk1 = *(const bf16x8*)(kp + 32 + quad * 8);
            f32x4 s4 = {0.f, 0.f, 0.f, 0.f};
            s4 = __builtin_amdgcn_mfma_f32_16x16x32_bf16(aq0, bk0, s4, 0, 0, 0);
            s4 = __builtin_amdgcn_mfma_f32_16x16x32_bf16(aq1, bk1, s4, 0, 0, 0);
            sc[t] = s4;
        }
        // stage V^T into buffer nc&1
        short* vtb = &Vt[nc & 1][0][0];
        #pragma unroll
        for (int t = 0; t < 8; t++) vtb[(size_t)(c80 * 8 + t) * 72 + j0] = vv0[t];
        #pragma unroll
        for (int t = 0; t < 8; t++) vtb[(size_t)((c80 + 4) * 8 + t) * 72 + j0] = vv1[t];
        __syncthreads();                       // Vt[nc&1] visible to all waves
        // online softmax per row
        #pragma unroll
        for (int r = 0; r < 4; r++) {
            int row = myrow + r;
            float mx = -INFINITY;
            #pragma unroll
            for (int t = 0; t < 4; t++) {
                int jj = t * 16 + lm;
                bool vis = true;
                if (c == 0) vis = (jj >= row);          // window lower bound
                if (c == 8) vis = (jj <= row);          // causal
                float v = vis ? sc[t][r] * SCALE : -INFINITY;
                sc[t][r] = v;
                mx = fmaxf(mx, v);
            }
            #pragma unroll
            for (int o = 1; o < 16; o <<= 1) mx = fmaxf(mx, __shfl_xor(mx, o));
            float mn = fmaxf(m[r], mx);                 // finite: >=1 visible key
            float al = __expf(m[r] - mn);
            float sum = 0.f;
            #pragma unroll
            for (int t = 0; t < 4; t++) {
                float pv_ = __expf(sc[t][r] - mn);
                sc[t][r] = pv_;                         // reuse sc as P
                sum += pv_;
            }
            #pragma unroll
            for (int o = 1; o < 16; o <<= 1) sum += __shfl_xor(sum, o);
            l[r] = l[r] * al + sum;
            m[r] = mn;
            #pragma unroll
            for (int t = 0; t < 4; t++) oacc[t][r] *= al;
        }
        // write wave-private P rows
        #pragma unroll
        for (int r = 0; r < 4; r++)
            #pragma unroll
            for (int t = 0; t < 4; t++)
                Pb[myrow + r][t * 16 + lm] = f2bs(sc[t][r]);
        asm volatile("s_waitcnt lgkmcnt(0)" ::: "memory");
        // PV
        bf16x8 ap0 = *(const bf16x8*)&Pb[wv * 16 + lm][quad * 8];
        bf16x8 ap1 = *(const bf16x8*)&Pb[wv * 16 + lm][32 + quad * 8];
        #pragma unroll
        for (int t = 0; t < 4; t++) {
            bf16x8 bv0 = *(const bf16x8*)(vtb + (size_t)(t * 16 + lm) * 72 + quad * 8);
            bf16x8 bv1 = *(const bf16x8*)(vtb + (size_t)(t * 16 + lm) * 72 + 32 + quad * 8);
            oacc[t] = __builtin_amdgcn_mfma_f32_16x16x32_bf16(ap0, bv0, oacc[t], 0, 0, 0);
            oacc[t] = __builtin_amdgcn_mfma_f32_16x16x32_bf16(ap1, bv1, oacc[t], 0, 0, 0);
        }
        nc++;
    }
    #pragma unroll
    for (int r = 0; r < 4; r++) {
        int spos = qb * 64 + myrow + r;
        float g2 = gates[((size_t)spos * HEADS + h) * 3 + 2];
        float f = g2 / l[r];
        #pragma unroll
        for (int t = 0; t < 4; t++)
            attn[(size_t)spos * (HEADS * DH) + h * DH + t * 16 + lm] += oacc[t][r] * f;
    }
}

// ---------------- launch ----------------
extern "C" void kernel_launch(void* const* d_in, const int* in_sizes, int n_in,
                              void* d_out, int out_size, void* d_ws, size_t ws_size,
                              hipStream_t stream) {
    const float* x      = (const float*)d_in[0];
    const float* rms_g  = (const float*)d_in[1];
    const float* W_qkv  = (const float*)d_in[2];
    const float* k_pos  = (const float*)d_in[3];
    const float* v_pos  = (const float*)d_in[4];
    const float* mem_kv = (const float*)d_in[5];
    const float* kW1    = (const float*)d_in[6];
    const float* kb1    = (const float*)d_in[7];
    const float* kW2    = (const float*)d_in[8];
    const float* kb2    = (const float*)d_in[9];
    const float* vW1    = (const float*)d_in[10];
    const float* vb1    = (const float*)d_in[11];
    const float* vW2    = (const float*)d_in[12];
    const float* vb2    = (const float*)d_in[13];
    const float* W_comb = (const float*)d_in[14];
    const float* b_comb = (const float*)d_in[15];
    const float* W_out  = (const float*)d_in[16];
    float* out = (float*)d_out;

    // workspace layout (floats) — R (1048576 fl) time-multiplexed:
    //   steps 1-2.5: xnb; steps 4-8: MLP scratch; steps 15-16: attnb.
    float* ws    = (float*)d_ws;
    float* xn    = ws;                                     // 2097152
    float* qkv   = xn    + (size_t)S * DIM;                // 2621440
    short* rqb   = (short*)(qkv + (size_t)S * QKVC);       // 2097152 sh = 1048576 fl
    short* rkb   = (short*)((float*)rqb + 1048576);        // 262144 sh = 131072 fl
    float* R     = (float*)rkb + 131072;                   // 1048576
    float* ck    = R     + 1048576;                        // 4224
    float* cv    = ck    + (size_t)KVH * (NCB + 1) * DH;   // 4224
    short* ck16  = (short*)(cv + (size_t)KVH * (NCB + 1) * DH);  // 4224 sh = 2112 fl
    short* cv16  = (short*)((float*)ck16 + 2112);          // 2112 fl
    float* imp   = (float*)cv16 + 2112;                    // 131072
    float* gates = imp   + (size_t)KVH * S * NCB;          // 98304
    float* attn  = gates + (size_t)S * HEADS * 3;          // 2097152
    int*   sel   = (int*)(attn + (size_t)S * HEADS * DH);  // 32768 ints = 8192 fl
    float* WT    = attn + (size_t)S * HEADS * DH + 8192;
    short* wqkvT = (short*)WT;                             // 1280*1024 bf16 = 655360 fl
    short* woutT = (short*)(WT + 655360);                  // 1024*1024 bf16 = 524288 fl
    short* wcombT= (short*)(WT + 655360 + 524288);         // 48*1024 bf16 = 24576 fl

    __hip_bfloat16* xnb   = (__hip_bfloat16*)R;            // dead after gates
    __hip_bfloat16* kcmb  = (__hip_bfloat16*)R;            // 131072 fl
    __hip_bfloat16* vcmb  = (__hip_bfloat16*)(R + 131072); // 131072 fl
    float* khid  = R + 262144;                             // 262144 fl
    float* vhid  = R + 524288;                             // 262144 fl
    float* ckb   = R + 786432;                             // 4096 fl
    float* cvb   = R + 790528;                             // 4096 fl (ends 794624)
    __hip_bfloat16* attnb = (__hip_bfloat16*)R;            // reused after fattn
    short* vbb   = (short*)imp;   // 262144 bf16 = 131072 fl (imp dead after select)
    float* partW1 = attn;   // 2097152 (attn live only from step 12)
    float* partW2 = imp;    // 131072  (imp live only steps 10-11)

    // 0. pre-transpose+cast weights to bf16 B^T
    transpose_cast_kernel<<<dim3(QKVC / 64, DIM / 64), 256, 0, stream>>>(W_qkv, wqkvT, DIM, QKVC);
    transpose_cast_kernel<<<dim3(DIM / 64, DIM / 64), 256, 0, stream>>>(W_out, woutT, DIM, DIM);
    transpose_cast_kernel<<<dim3(1, DIM / 64), 256, 0, stream>>>(W_comb, wcombT, DIM, HEADS * 3);
    // 1. RMSNorm (fp32 + bf16)
    rmsnorm_kernel<<<S, 256, 0, stream>>>(x, rms_g, xn, xnb);
    // 2. QKV projection (bf16 B^T MFMA)
    gemm_bt_kernel<64, 64, 2, 2, 0><<<dim3(QKVC / 64, S / 64), 256, 0, stream>>>(
        xnb, wqkvT, nullptr, qkv, S, QKVC, DIM);
    // 2.5 gates = sigmoid(xn @ W_comb + b_comb)
    gemm_bt_kernel<64, 64, 2, 2, 2><<<dim3(1, S / 64), 256, 0, stream>>>(
        xnb, wcombT, b_comb, gates, S, HEADS * 3, DIM);
    // 3. rotary -> bf16 rqb, rkb
    rotary_kernel<<<S, 256, 0, stream>>>(qkv, rqb, rkb);
    // 4. compress-MLP inputs (bf16)
    build_cmat_kernel<<<KVH * NCB, 256, 0, stream>>>(qkv, k_pos, v_pos, kcmb, vcmb);
    // 5. k-MLP W1 (bf16 MFMA, split-K 8)
    gemm_mfma_kernel<64, 128, 1, 4><<<dim3(CDIM / 128, 1, 8), 256, 0, stream>>>(
        kcmb, kW1, partW1, 64, CDIM, CDIM, CDIM / 8);
    reduce_splitk_kernel<1><<<(64 * CDIM + 255) / 256, 256, 0, stream>>>(
        partW1, kb1, khid, 64 * CDIM, CDIM, 8);
    // 6. k-MLP W2 (fp32 split-K 32)
    gemm_splitk_kernel<<<dim3(1, 1, 32), 256, 0, stream>>>(khid, kW2, partW2, 64, DH, CDIM, CDIM / 32);
    reduce_splitk_kernel<0><<<(64 * DH + 255) / 256, 256, 0, stream>>>(partW2, kb2, ckb, 64 * DH, DH, 32);
    // 7. v-MLP
    gemm_mfma_kernel<64, 128, 1, 4><<<dim3(CDIM / 128, 1, 8), 256, 0, stream>>>(
        vcmb, vW1, partW1, 64, CDIM, CDIM, CDIM / 8);
    reduce_splitk_kernel<1><<<(64 * CDIM + 255) / 256, 256, 0, stream>>>(
        partW1, vb1, vhid, 64 * CDIM, CDIM, 8);
    gemm_splitk_kernel<<<dim3(1, 1, 32), 256, 0, stream>>>(vhid, vW2, partW2, 64, DH, CDIM, CDIM / 32);
    reduce_splitk_kernel<0><<<(64 * DH + 255) / 256, 256, 0, stream>>>(partW2, vb2, cvb, 64 * DH, DH, 32);
    // 8. assemble ck/cv (fp32 + bf16) with mem tokens
    assemble_kernel<<<(KVH * (NCB + 1) * DH + 255) / 256, 256, 0, stream>>>(
        ckb, cvb, mem_kv, ck, cv, ck16, cv16);
    // 10. block importance
    imp_kernel<<<dim3(KVH, S), 64, 0, stream>>>(qkv, ck, imp);
    // 11. top-8 selection
    select_kernel<<<(KVH * S + 255) / 256, 256, 0, stream>>>(imp, sel);
    // 11.5 cast V cols -> bf16 vbb
    cast_v_kernel<<<(S * KVH * DH / 4 + 255) / 256, 256, 0, stream>>>(qkv, vbb);
    // 12. compressed attention, MFMA (writes attn = g0*c_out)
    cattn_kernel<<<dim3(HEADS, S / 64), 256, 0, stream>>>(qkv, ck16, cv16, gates, attn);
    // 13. fine attention, 2-wave split-key flash (attn += g1*f_out)
    fattn_kernel<<<dim3(KVH, S), 128, 0, stream>>>(rqb, rkb, vbb, sel, gates, attn);
    // 14. sliding window, MFMA, 1 barrier/chunk (attn += g2*s_out)
    sattn_kernel<<<dim3(HEADS, S / 64), 256, 0, stream>>>(rqb, rkb, vbb, gates, attn);
    // 15. cast attn -> bf16
    cast_bf16_kernel<<<(S * HEADS * DH / 4 + 255) / 256, 256, 0, stream>>>(
        attn, attnb, S * HEADS * DH / 4);
    // 16. output projection (bf16 B^T MFMA)
    gemm_bt_kernel<64, 64, 2, 2, 0><<<dim3(DIM / 64, S / 64), 256, 0, stream>>>(
        attnb, woutT, nullptr, out, S, DIM, DIM);
}